// Round 6
// baseline (334.538 us; speedup 1.0000x reference)
//
#include <hip/hip_runtime.h>
#include <hip/hip_fp16.h>
#include <math.h>
#include <stdint.h>

#define BB 32
#define NN 512
#define DDIM 512
#define HH 8
#define DK 64

typedef __attribute__((ext_vector_type(8))) _Float16 half8;
typedef __attribute__((ext_vector_type(4))) float floatx4;
typedef unsigned short ushort_t;
typedef unsigned int uint_t;

// async global->LDS, 16B/lane; LDS dest = wave-uniform base + lane*16
__device__ __forceinline__ void gl_lds16(const void* g, void* l) {
    __builtin_amdgcn_global_load_lds(
        (const __attribute__((address_space(1))) uint_t*)g,
        (__attribute__((address_space(3))) uint_t*)l,
        16, 0, 0);
}

__device__ __forceinline__ uint_t pkh(float a, float b) {  // 2xf32 -> f16x2, 1 inst
    return __builtin_bit_cast(uint_t, __builtin_amdgcn_cvt_pkrtz(a, b));
}

__device__ __forceinline__ float h2f(ushort_t u) {
    return __half2float(__ushort_as_half(u));
}

// ---------------------------------------------------------------------------
// Fused prep: y==0 cvt x->fp16 (4096 blocks); y==1 dist->fp16 T (4096);
// y==2 cvt 4 weights->fp16 (512 active blocks).
// T[bin] = (dw[bin]-3)*log2e  (constant-max softmax, base-2)
// ---------------------------------------------------------------------------
__global__ __launch_bounds__(256) void prep(
    const float* __restrict__ x, const float* __restrict__ dist,
    const float* __restrict__ dw,
    const float* __restrict__ Wq, const float* __restrict__ Wk,
    const float* __restrict__ Wv, const float* __restrict__ Wo,
    ushort_t* __restrict__ xb, ushort_t* __restrict__ Tm,
    ushort_t* __restrict__ wqb, ushort_t* __restrict__ wkb,
    ushort_t* __restrict__ wvb, ushort_t* __restrict__ wob) {
    __shared__ ushort_t dwh[21];
    const int tid = threadIdx.x, bx = blockIdx.x, y = blockIdx.y;
    if (y == 0) {
        const int i = bx * 256 + tid;
        const float4 a = ((const float4*)x)[i * 2 + 0];
        const float4 b = ((const float4*)x)[i * 2 + 1];
        uint4 o;
        o.x = pkh(a.x, a.y); o.y = pkh(a.z, a.w);
        o.z = pkh(b.x, b.y); o.w = pkh(b.z, b.w);
        *(uint4*)(xb + i * 8) = o;
    } else if (y == 1) {
        if (tid < 21)
            dwh[tid] = __half_as_ushort(__float2half((dw[tid] - 3.0f) * 1.44269504f));
        __syncthreads();
        const int i = bx * 256 + tid;
        const float4 a = ((const float4*)dist)[i * 2 + 0];
        const float4 b = ((const float4*)dist)[i * 2 + 1];
        float dv[8] = {a.x, a.y, a.z, a.w, b.x, b.y, b.z, b.w};
        ushort_t h[8];
        #pragma unroll
        for (int j = 0; j < 8; ++j) {
            int bin = (int)(dv[j] / 5.0f);
            bin = bin < 0 ? 0 : (bin > 20 ? 20 : bin);
            h[j] = dwh[bin];
        }
        uint4 o;
        o.x = (uint_t)h[0] | ((uint_t)h[1] << 16);
        o.y = (uint_t)h[2] | ((uint_t)h[3] << 16);
        o.z = (uint_t)h[4] | ((uint_t)h[5] << 16);
        o.w = (uint_t)h[6] | ((uint_t)h[7] << 16);
        *(uint4*)(Tm + i * 8) = o;
    } else {
        if (bx >= 512) return;
        const float* s; ushort_t* d;
        const int w = bx >> 7;
        if (w == 0)      { s = Wq; d = wqb; }
        else if (w == 1) { s = Wk; d = wkb; }
        else if (w == 2) { s = Wv; d = wvb; }
        else             { s = Wo; d = wob; }
        const int i = (bx & 127) * 256 + tid;
        const float4 a = ((const float4*)s)[i * 2 + 0];
        const float4 b = ((const float4*)s)[i * 2 + 1];
        uint4 o;
        o.x = pkh(a.x, a.y); o.y = pkh(a.z, a.w);
        o.z = pkh(b.x, b.y); o.w = pkh(b.z, b.w);
        *(uint4*)(d + i * 8) = o;
    }
}

// ---------------------------------------------------------------------------
// GEMM core (fp16): 128x128 tile, BK=32, global_load_lds, XOR chunk swizzle.
// SWAPSEL=0: frag A from Bs (feat rows) -> D[feat][token]
// SWAPSEL=1: frag A from As (token rows) -> D[token][feat] (for V^T output)
// ---------------------------------------------------------------------------
#define GEMM_CORE(Aptr, Wptr, SWAPSEL)                                                  \
    __shared__ ushort_t As[128 * 32];                                                   \
    __shared__ ushort_t Bs[128 * 32];                                                   \
    const int tid = threadIdx.x;                                                        \
    const int lane = tid & 63, wid = tid >> 6;                                          \
    const int quad = lane >> 4, l15 = lane & 15;                                        \
    const int m0 = blockIdx.x * 128, n0 = blockIdx.y * 128;                             \
    const int wy = wid >> 1, wx = wid & 1;                                              \
    const ushort_t* pA = (SWAPSEL) ? As : Bs;                                           \
    const ushort_t* pB = (SWAPSEL) ? Bs : As;                                           \
    floatx4 acc[4][4];                                                                  \
    _Pragma("unroll") for (int i = 0; i < 4; ++i)                                       \
        _Pragma("unroll") for (int j = 0; j < 4; ++j)                                   \
            _Pragma("unroll") for (int r = 0; r < 4; ++r) acc[i][j][r] = 0.f;           \
    for (int k0 = 0; k0 < DDIM; k0 += 32) {                                             \
        __syncthreads();                                                                \
        _Pragma("unroll") for (int j = 0; j < 4; ++j) {                                 \
            const int t = wid * 4 + j;                                                  \
            const int rowi = ((t & 7) << 4) + (lane >> 2);                              \
            const int cd = (lane & 3) ^ ((rowi >> 1) & 3);                              \
            if (t < 8)                                                                  \
                gl_lds16(Aptr + (size_t)(m0 + rowi) * DDIM + k0 + cd * 8,               \
                         (char*)As + ((t & 7) << 10));                                  \
            else                                                                        \
                gl_lds16(Wptr + (size_t)(n0 + rowi) * DDIM + k0 + cd * 8,               \
                         (char*)Bs + ((t & 7) << 10));                                  \
        }                                                                               \
        __syncthreads();                                                                \
        half8 fa[4], fb[4];                                                             \
        _Pragma("unroll") for (int fi = 0; fi < 4; ++fi) {                              \
            const int r = wy * 64 + fi * 16 + l15;                                      \
            fa[fi] = *(const half8*)((const char*)pA + r * 64 +                         \
                                     ((quad ^ ((r >> 1) & 3)) << 4));                   \
        }                                                                               \
        _Pragma("unroll") for (int ti = 0; ti < 4; ++ti) {                              \
            const int r = wx * 64 + ti * 16 + l15;                                      \
            fb[ti] = *(const half8*)((const char*)pB + r * 64 +                         \
                                     ((quad ^ ((r >> 1) & 3)) << 4));                   \
        }                                                                               \
        _Pragma("unroll") for (int fi = 0; fi < 4; ++fi)                                \
            _Pragma("unroll") for (int ti = 0; ti < 4; ++ti)                            \
                acc[fi][ti] = __builtin_amdgcn_mfma_f32_16x16x32_f16(                   \
                    fa[fi], fb[ti], acc[fi][ti], 0, 0, 0);                              \
    }

// QKV projection. z 0/1: Q,K fp16 [token][512]. z==2: V written directly
// transposed -> Vt[(b*8+h)*64+dk][512] via swapped frag sources.
__global__ __launch_bounds__(256) void gemm_qkv(
    const ushort_t* __restrict__ A,
    const ushort_t* __restrict__ W0, const ushort_t* __restrict__ W1,
    const ushort_t* __restrict__ W2,
    const float* __restrict__ b0, const float* __restrict__ b1,
    const float* __restrict__ b2,
    ushort_t* __restrict__ o0, ushort_t* __restrict__ o1,
    ushort_t* __restrict__ vt) {
    const ushort_t* W; const float* bias;
    if (blockIdx.z == 0)      { W = W0; bias = b0; }
    else if (blockIdx.z == 1) { W = W1; bias = b1; }
    else                      { W = W2; bias = b2; }
    const bool isv = (blockIdx.z == 2);
    GEMM_CORE(A, W, isv)
    if (!isv) {
        ushort_t* dst = (blockIdx.z == 0) ? o0 : o1;
        #pragma unroll
        for (int fi = 0; fi < 4; ++fi) {
            const int f = n0 + wy * 64 + fi * 16 + quad * 4;
            const float4 b4 = *(const float4*)&bias[f];
            #pragma unroll
            for (int ti = 0; ti < 4; ++ti) {
                const int token = m0 + wx * 64 + ti * 16 + l15;
                uint2 v;
                v.x = pkh(acc[fi][ti][0] + b4.x, acc[fi][ti][1] + b4.y);
                v.y = pkh(acc[fi][ti][2] + b4.z, acc[fi][ti][3] + b4.w);
                *(uint2*)&dst[(size_t)token * DDIM + f] = v;
            }
        }
    } else {
        // acc[fi][ti]: rows m = tokens (wy,fi,quad*4+r), cols n = feats (wx,ti,l15)
        #pragma unroll
        for (int ti = 0; ti < 4; ++ti) {
            const int f = n0 + wx * 64 + ti * 16 + l15;
            const float bv = bias[f];
            const int hh = f >> 6, dk = f & 63;
            #pragma unroll
            for (int fi = 0; fi < 4; ++fi) {
                const int token = m0 + wy * 64 + fi * 16 + quad * 4;
                const int bidx = token >> 9, n = token & 511;
                uint2 v;
                v.x = pkh(acc[fi][ti][0] + bv, acc[fi][ti][1] + bv);
                v.y = pkh(acc[fi][ti][2] + bv, acc[fi][ti][3] + bv);
                *(uint2*)&vt[((size_t)((bidx * HH + hh) * DK + dk)) * NN + n] = v;
            }
        }
    }
}

// Output projection -> fp32 [token][512]
__global__ __launch_bounds__(256) void gemm_out(
    const ushort_t* __restrict__ A, const ushort_t* __restrict__ Wo,
    const float* __restrict__ bo, float* __restrict__ dst) {
    GEMM_CORE(A, Wo, false)
    #pragma unroll
    for (int fi = 0; fi < 4; ++fi) {
        const int f = n0 + wy * 64 + fi * 16 + quad * 4;
        const float4 b4 = *(const float4*)&bo[f];
        #pragma unroll
        for (int ti = 0; ti < 4; ++ti) {
            const int token = m0 + wx * 64 + ti * 16 + l15;
            float4 v;
            v.x = acc[fi][ti][0] + b4.x; v.y = acc[fi][ti][1] + b4.y;
            v.z = acc[fi][ti][2] + b4.z; v.w = acc[fi][ti][3] + b4.w;
            *(float4*)&dst[(size_t)token * DDIM + f] = v;
        }
    }
}

// ---------------------------------------------------------------------------
// Barrier-free MFMA attention. Grid (HH, BB, 4), 256 thr (4 waves).
// Wave w of quarter qz owns q rows qz*128 + w*32 .. +31 (2 qsets of 16).
// K/V^T fragments loaded DIRECT from global (L1/L2-resident; quad-group
// addresses coalesce to 64B lines). Only LDS: 8KB wave-private P roundtrip.
// No __syncthreads anywhere. Constant-max softmax (folded into fp16 T).
// ---------------------------------------------------------------------------
__global__ __launch_bounds__(256, 4) void attn_fused(
    const ushort_t* __restrict__ Qg, const ushort_t* __restrict__ Kg,
    const ushort_t* __restrict__ Vtg, const ushort_t* __restrict__ Tg,
    ushort_t* __restrict__ aout) {
    __shared__ ushort_t Ps[4 * 1024];   // 4 waves x 16 rows x 128B

    const int tid = threadIdx.x, lane = tid & 63, wid = tid >> 6;
    const int quad = lane >> 4, l15 = lane & 15;
    const int h = blockIdx.x, b = blockIdx.y, qz = blockIdx.z;
    const int qbase = qz * 128 + wid * 32;
    const float K1 = 0.18033688f;       // 0.125 * log2(e)

    // Q fragments (B operand), direct from global
    half8 bq[2][2];
    #pragma unroll
    for (int qs = 0; qs < 2; ++qs) {
        const ushort_t* qp =
            Qg + (size_t)(b * NN + qbase + qs * 16 + l15) * DDIM + h * DK;
        bq[qs][0] = *(const half8*)(qp + quad * 8);
        bq[qs][1] = *(const half8*)(qp + 32 + quad * 8);
    }

    const ushort_t* kbase = Kg + (size_t)(b * NN) * DDIM + h * DK;
    const ushort_t* vbase = Vtg + (size_t)((b * HH + h) * DK) * NN;

    float lsum[2] = {0.f, 0.f};
    floatx4 O[2][4];
    #pragma unroll
    for (int qs = 0; qs < 2; ++qs)
        #pragma unroll
        for (int ni = 0; ni < 4; ++ni)
            #pragma unroll
            for (int r = 0; r < 4; ++r) O[qs][ni][r] = 0.f;

    char* const pbase = (char*)Ps + wid * 2048;
    const int swk = l15 & 7;

    for (int kt = 0; kt < 8; ++kt) {
        #pragma unroll
        for (int qs = 0; qs < 2; ++qs) {
            // K fragments (A operand), direct from global
            half8 kf[2][4];
            #pragma unroll
            for (int ks = 0; ks < 2; ++ks)
                #pragma unroll
                for (int f = 0; f < 4; ++f)
                    kf[ks][f] = *(const half8*)(
                        kbase + (size_t)(kt * 64 + f * 16 + l15) * DDIM +
                        (ks * 4 + quad) * 8);
            // T bias words
            const ushort_t* tq =
                Tg + (size_t)(b * NN + qbase + qs * 16 + l15) * NN + kt * 64;
            uint2 tv[4];
            #pragma unroll
            for (int f = 0; f < 4; ++f)
                tv[f] = *(const uint2*)(tq + f * 16 + quad * 4);

            // S^T = K·Q^T
            floatx4 S[4];
            #pragma unroll
            for (int f = 0; f < 4; ++f)
                #pragma unroll
                for (int r = 0; r < 4; ++r) S[f][r] = 0.f;
            #pragma unroll
            for (int ks = 0; ks < 2; ++ks)
                #pragma unroll
                for (int f = 0; f < 4; ++f)
                    S[f] = __builtin_amdgcn_mfma_f32_16x16x32_f16(
                        kf[ks][f], bq[qs][ks], S[f], 0, 0, 0);

            // V^T fragments (A operand), direct from global (issued early)
            half8 vf[2][4];
            #pragma unroll
            for (int ks = 0; ks < 2; ++ks)
                #pragma unroll
                for (int ni = 0; ni < 4; ++ni)
                    vf[ks][ni] = *(const half8*)(
                        vbase + (size_t)(ni * 16 + l15) * NN + kt * 64 +
                        (ks * 4 + quad) * 8);

            // p = exp2(s*K1 + T); publish P fp16 (wave-private rows)
            float ls = 0.f;
            #pragma unroll
            for (int f = 0; f < 4; ++f) {
                const float t0 = h2f((ushort_t)(tv[f].x));
                const float t1 = h2f((ushort_t)(tv[f].x >> 16));
                const float t2 = h2f((ushort_t)(tv[f].y));
                const float t3 = h2f((ushort_t)(tv[f].y >> 16));
                const float p0 = exp2f(S[f][0] * K1 + t0);
                const float p1 = exp2f(S[f][1] * K1 + t1);
                const float p2 = exp2f(S[f][2] * K1 + t2);
                const float p3 = exp2f(S[f][3] * K1 + t3);
                ls += (p0 + p1) + (p2 + p3);
                uint2 pw;
                pw.x = pkh(p0, p1);
                pw.y = pkh(p2, p3);
                *(uint2*)(pbase + l15 * 128 +
                          (((f * 4 + quad) ^ (swk << 1)) << 3)) = pw;
            }
            lsum[qs] += ls;

            // O^T += V^T·P
            #pragma unroll
            for (int ks = 0; ks < 2; ++ks) {
                const half8 bp = *(const half8*)(pbase + l15 * 128 +
                                                 (((ks * 4 + quad) ^ swk) << 4));
                #pragma unroll
                for (int ni = 0; ni < 4; ++ni)
                    O[qs][ni] = __builtin_amdgcn_mfma_f32_16x16x32_f16(
                        vf[ks][ni], bp, O[qs][ni], 0, 0, 0);
            }
        }
    }

    // epilogue: reduce l over quads, normalize, write fp16 [token][512]
    #pragma unroll
    for (int qs = 0; qs < 2; ++qs) {
        float l = lsum[qs];
        l += __shfl_xor(l, 16);
        l += __shfl_xor(l, 32);
        const float inv = 1.0f / l;
        const size_t orow =
            (size_t)(b * NN + qbase + qs * 16 + l15) * DDIM + h * DK;
        #pragma unroll
        for (int ni = 0; ni < 4; ++ni) {
            uint2 ov;
            ov.x = pkh(O[qs][ni][0] * inv, O[qs][ni][1] * inv);
            ov.y = pkh(O[qs][ni][2] * inv, O[qs][ni][3] * inv);
            *(uint2*)&aout[orow + ni * 16 + quad * 4] = ov;
        }
    }
}

extern "C" void kernel_launch(void* const* d_in, const int* in_sizes, int n_in,
                              void* d_out, int out_size, void* d_ws, size_t ws_size,
                              hipStream_t stream) {
    const float* x    = (const float*)d_in[0];
    const float* dist = (const float*)d_in[1];
    const float* Wq   = (const float*)d_in[2];
    const float* bq   = (const float*)d_in[3];
    const float* Wk   = (const float*)d_in[4];
    const float* bk   = (const float*)d_in[5];
    const float* Wv   = (const float*)d_in[6];
    const float* bv   = (const float*)d_in[7];
    const float* Wo   = (const float*)d_in[8];
    const float* bo   = (const float*)d_in[9];
    const float* dw   = (const float*)d_in[10];
    float* out = (float*)d_out;

    const size_t NELT = (size_t)BB * NN * DDIM;   // 8388608
    const size_t WELT = (size_t)DDIM * DDIM;      // 262144
    ushort_t* xb  = (ushort_t*)d_ws;              // fp16 x; aliased by ab later
    ushort_t* wqb = xb + NELT;
    ushort_t* wkb = wqb + WELT;
    ushort_t* wvb = wkb + WELT;
    ushort_t* wob = wvb + WELT;
    ushort_t* qb  = wob + WELT;
    ushort_t* kb  = qb + NELT;
    ushort_t* vt  = kb + NELT;                    // V^T fp16 [(b*8+h)*64+dk][512]
    ushort_t* Tm  = vt + NELT;                    // fp16 bias matrix
    ushort_t* ab  = xb;                           // alias: xb dead after gemm_qkv

    prep<<<dim3(4096, 3), 256, 0, stream>>>(x, dist, dw, Wq, Wk, Wv, Wo,
                                            xb, Tm, wqb, wkb, wvb, wob);
    gemm_qkv<<<dim3(128, 4, 3), 256, 0, stream>>>(xb, wqb, wkb, wvb, bq, bk, bv,
                                                  qb, kb, vt);
    attn_fused<<<dim3(HH, BB, 4), 256, 0, stream>>>(qb, kb, vt, Tm, ab);
    gemm_out<<<dim3(128, 4), 256, 0, stream>>>(ab, wob, bo, out);
}